// Round 19
// baseline (318.086 us; speedup 1.0000x reference)
//
#include <hip/hip_runtime.h>
#include <math.h>

#define HH 512
#define WW 512
#define NB 64
#define HW (HH*WW)

struct GaussK { float k[13]; };

__device__ __forceinline__ float idenv(int i) {
    return (float)(2*i - (WW-1)) / (float)(WW-1);
}

#define DEF_OFF ((float)((2.0 + 4.0/511.0)/2.0))
#define BOUND   ((float)(2.0/512.0*8.0))

typedef float vf2 __attribute__((ext_vector_type(2), aligned(4)));
typedef float vf4 __attribute__((ext_vector_type(4), aligned(4)));

// horizontal 13-tap conv of one row held as a[8] per lane (cols 8l..8l+7),
// halo via neighbor-lane shuffles, reflect at row ends.
__device__ __forceinline__ void hconv_row(const float (&a)[8], int lane, const GaussK& gk, float (&o)[8]) {
    float win[20];
    #pragma unroll
    for (int i = 0; i < 6; ++i) {
        float v = __shfl_up(a[i+2], 1, 64);
        win[i] = (lane == 0) ? a[6-i] : v;
    }
    #pragma unroll
    for (int i = 6; i < 14; ++i) win[i] = a[i-6];
    #pragma unroll
    for (int i = 14; i < 20; ++i) {
        float v = __shfl_down(a[i-14], 1, 64);
        win[i] = (lane == 63) ? a[20-i] : v;
    }
    #pragma unroll
    for (int j = 0; j < 8; ++j) {
        float acc = 0.f;
        #pragma unroll
        for (int i = 0; i < 13; ++i) acc = fmaf(gk.k[i], win[j+i], acc);
        o[j] = acc;
    }
}

// x-channel pipeline for one row: hconv (incl col-1) + relu-diff scan + clips.
__device__ __forceinline__ void xscan_row(const float (&a)[8], int lane, const GaussK& gk, float* row0) {
    float win[21];
    #pragma unroll
    for (int i = 0; i < 7; ++i) {
        float v = __shfl_up(a[i+1], 1, 64);
        win[i] = (lane == 0) ? a[7-i] : v;
    }
    #pragma unroll
    for (int i = 0; i < 8; ++i) win[7+i] = a[i];
    #pragma unroll
    for (int i = 15; i < 21; ++i) {
        float v = __shfl_down(a[i-15], 1, 64);
        win[i] = (lane == 63) ? a[21-i] : v;
    }
    float s[9];
    #pragma unroll
    for (int j = 0; j < 9; ++j) {
        float acc = 0.f;
        #pragma unroll
        for (int i = 0; i < 13; ++i) acc = fmaf(gk.k[i], win[j+i], acc);
        s[j] = acc + idenv(8*lane - 1 + j) + DEF_OFF;
    }
    if (lane == 0) s[0] = 0.f;

    float qs[8], q = 0.f;
    #pragma unroll
    for (int j = 1; j < 9; ++j) { q += fmaxf(s[j] - s[j-1], 0.f); qs[j-1] = q; }
    float inc = q;
    #pragma unroll
    for (int d = 1; d < 64; d <<= 1) {
        float t = __shfl_up(inc, d, 64);
        if (lane >= d) inc += t;
    }
    float excl = inc - q;

    float4 g0, g1;
    float* gp0 = (float*)&g0;
    float* gp1 = (float*)&g1;
    #pragma unroll
    for (int j = 0; j < 8; ++j) {
        int wcol = lane*8 + j;
        float sx = excl + qs[j];
        float p = sx - DEF_OFF - idenv(wcol);
        p = fminf(fmaxf(p, -BOUND), BOUND);
        float g = p + idenv(wcol);
        g = fminf(fmaxf(g, -1.f), 1.f);
        if (j < 4) gp0[j] = g; else gp1[j-4] = g;
    }
    *(float4*)(row0 + lane*8)     = g0;
    *(float4*)(row0 + lane*8 + 4) = g1;
}

// ---- fused prep: vblur(ch0)+hblur+row-scan -> plane0  AND  hblur(ch1) -> plane1 ----
__global__ void __launch_bounds__(256) k_prep(const float* __restrict__ prim, float* __restrict__ out, GaussK gk) {
    int lane = threadIdx.x & 63;
    int bid  = (int)blockIdx.x;                  // 2048 blocks
    int work = (bid & 7)*256 + (bid >> 3);       // XCD-chunked, bijective
    int gw   = work*4 + ((int)threadIdx.x >> 6); // 0..8191
    int b    = gw >> 7;
    int h0   = (gw & 127)*4;

    const float4* src0 = (const float4*)(prim + (size_t)b*2*HW);
    const float*  src1 = prim + ((size_t)b*2 + 1)*HW;
    float* plane0 = out + (size_t)b*3*HW;
    float* plane1 = out + ((size_t)b*3 + 1)*HW;

    float a[4][8];
    #pragma unroll
    for (int r = 0; r < 4; ++r)
        #pragma unroll
        for (int j = 0; j < 8; ++j) a[r][j] = 0.f;

    #pragma unroll
    for (int i = 0; i < 16; ++i) {
        int rr = h0 - 6 + i;
        rr = rr < 0 ? -rr : (rr > HH-1 ? 2*(HH-1) - rr : rr);
        float4 u0 = src0[(size_t)rr*128 + 2*lane];
        float4 u1 = src0[(size_t)rr*128 + 2*lane + 1];
        float vv[8] = {u0.x,u0.y,u0.z,u0.w,u1.x,u1.y,u1.z,u1.w};
        #pragma unroll
        for (int r = 0; r < 4; ++r) {
            if (i >= r && i <= r + 12) {
                #pragma unroll
                for (int j = 0; j < 8; ++j) a[r][j] = fmaf(gk.k[i-r], vv[j], a[r][j]);
            }
        }
    }

    #pragma unroll
    for (int r = 0; r < 4; ++r) {
        const float4* c4 = (const float4*)(src1 + (size_t)(h0+r)*WW);
        float4 u0 = c4[2*lane];
        float4 u1 = c4[2*lane + 1];
        float c[8] = {u0.x,u0.y,u0.z,u0.w,u1.x,u1.y,u1.z,u1.w};
        float o[8];
        hconv_row(c, lane, gk, o);
        float* row1 = plane1 + (size_t)(h0+r)*WW;
        *(float4*)(row1 + lane*8)     = make_float4(o[0],o[1],o[2],o[3]);
        *(float4*)(row1 + lane*8 + 4) = make_float4(o[4],o[5],o[6],o[7]);
    }

    #pragma unroll
    for (int r = 0; r < 4; ++r)
        xscan_row(a[r], lane, gk, plane0 + (size_t)(h0+r)*WW);
}

// ---- fused y-scan + paired bilinear sample ----
// Phase 1: 16 waves segmented column scan -> grid-y stored to plane2 (L2-hot).
// Phase 2: 2 adjacent x-px per thread: float2 grid loads, float2 nt stores,
//          and (smooth-field common case) one float4 gather per (ch,row) pair
//          covering both px with STATIC indices; per-px vf2 fallback otherwise.
__global__ void __launch_bounds__(1024) k_yssamp(const float* __restrict__ image, float* __restrict__ out, GaussK gk) {
    __shared__ float segsum[16][64];
    int bid  = (int)blockIdx.x;          // 512 blocks
    int work = (bid & 7)*64 + (bid >> 3);// XCD j owns batches j*8..j*8+7
    int b    = work >> 3;
    int wt   = work & 7;
    int c0   = wt*64;
    int lane = threadIdx.x & 63;
    int ws   = threadIdx.x >> 6;         // 0..15
    int w    = c0 + lane;
    const float* p1 = out + ((size_t)b*3 + 1)*HW + w;
    float*       p2 = out + ((size_t)b*3 + 2)*HW + w;
    int r0 = ws*32;

    // ---------- phase 1: column scan -> plane2 ----------
    {
        float v[45];                          // plane1 rows r0-7 .. r0+37, reflected
        #pragma unroll
        for (int j = 0; j < 45; ++j) {
            int r = r0 - 7 + j;
            r = r < 0 ? -r : (r > HH-1 ? 2*(HH-1) - r : r);
            v[j] = p1[(size_t)r*WW];
        }
        float sprev;
        if (ws == 0) {
            sprev = 0.f;
        } else {
            float acc = 0.f;
            #pragma unroll
            for (int i = 0; i < 13; ++i) acc = fmaf(gk.k[i], v[i], acc);
            sprev = acc + idenv(r0 - 1) + DEF_OFF;
        }
        float q[32];
        float run = 0.f;
        #pragma unroll
        for (int n = 0; n < 32; ++n) {
            float acc = 0.f;
            #pragma unroll
            for (int i = 0; i < 13; ++i) acc = fmaf(gk.k[i], v[n+1+i], acc);
            float s = acc + idenv(r0 + n) + DEF_OFF;
            run += fmaxf(s - sprev, 0.f);
            q[n] = run;
            sprev = s;
        }
        segsum[ws][lane] = run;
        __syncthreads();
        float off = 0.f;
        for (int k = 0; k < ws; ++k) off += segsum[k][lane];
        #pragma unroll
        for (int n = 0; n < 32; ++n) {
            int h = r0 + n;
            float p = off + q[n] - DEF_OFF - idenv(h);
            p = fminf(fmaxf(p, -BOUND), BOUND);
            float g = p + idenv(h);
            g = fminf(fmaxf(g, -1.f), 1.f);
            p2[(size_t)h*WW] = g;            // plain store: L2-resident
        }
    }
    __syncthreads();                          // plane2 visible block-wide

    // ---------- phase 2: paired sampling ----------
    const float* ib = image + (size_t)b*3*HW;
    float*       ob = out   + (size_t)b*3*HW;
    int tid = (int)threadIdx.x;
    int cp  = tid & 31;                  // col-pair index
    int rg  = tid >> 5;                  // 0..31 -> rows rg*16 .. rg*16+15
    int col = c0 + 2*cp;

    for (int rr = 0; rr < 16; ++rr) {
        int h = rg*16 + rr;
        size_t off = (size_t)h*WW + col;
        vf2 gx2 = *(const vf2*)(ob + off);          // plane0 (read before overwrite)
        vf2 gy2 = *(const vf2*)(ob + 2*HW + off);   // plane2 (L2-hot)

        float fx0 = (gx2.x + 1.f) * 0.5f * (float)(WW-1);
        float fx1 = (gx2.y + 1.f) * 0.5f * (float)(WW-1);
        float fy0 = (gy2.x + 1.f) * 0.5f * (float)(HH-1);
        float fy1 = (gy2.y + 1.f) * 0.5f * (float)(HH-1);
        float xf0 = floorf(fx0), xf1 = floorf(fx1);
        float yf0 = floorf(fy0), yf1 = floorf(fy1);
        float wx0 = fx0 - xf0, wx1 = fx1 - xf1;
        float wy0 = fy0 - yf0, wy1 = fy1 - yf1;
        int x00 = (int)xf0, x01 = (int)xf1;
        int y00 = (int)yf0, y01 = (int)yf1;
        bool sh0 = x00 > WW-2, sh1 = x01 > WW-2;    // x0==511 => wx==0 exactly
        int xb0 = sh0 ? WW-2 : x00, xb1 = sh1 ? WW-2 : x01;
        int y10 = y00 + 1 > HH-1 ? HH-1 : y00 + 1;
        int y11 = y01 + 1 > HH-1 ? HH-1 : y01 + 1;

        float w110 = wx0*wy0, w010 = wx0 - w110, w100 = wy0 - w110, w000 = 1.f - wx0 - wy0 + w110;
        float w111 = wx1*wy1, w011 = wx1 - w111, w101 = wy1 - w111, w001 = 1.f - wx1 - wy1 + w111;

        float r0c[3], r1c[3];
        if (y00 == y01 && xb1 == xb0 + 1 && xb0 <= WW-4) {
            // shared float4 path: px0 taps t.x,t.y; px1 taps t.y,t.z (no shx possible here)
            size_t gt = (size_t)y00*WW + xb0;
            size_t gb = (size_t)y10*WW + xb0;
            #pragma unroll
            for (int c = 0; c < 3; ++c) {
                const float* ip = ib + (size_t)c*HW;
                vf4 t  = *(const vf4*)(ip + gt);
                vf4 bo = *(const vf4*)(ip + gb);
                r0c[c] = t.x*w000 + t.y*w010 + bo.x*w100 + bo.y*w110;
                r1c[c] = t.y*w001 + t.z*w011 + bo.y*w101 + bo.z*w111;
            }
        } else {
            size_t g00 = (size_t)y00*WW + xb0, g10 = (size_t)y10*WW + xb0;
            size_t g01 = (size_t)y01*WW + xb1, g11 = (size_t)y11*WW + xb1;
            #pragma unroll
            for (int c = 0; c < 3; ++c) {
                const float* ip = ib + (size_t)c*HW;
                vf2 t0 = *(const vf2*)(ip + g00);
                vf2 b0 = *(const vf2*)(ip + g10);
                vf2 t1 = *(const vf2*)(ip + g01);
                vf2 b1 = *(const vf2*)(ip + g11);
                float a000 = sh0 ? t0.y : t0.x;
                float a100 = sh0 ? b0.y : b0.x;
                r0c[c] = a000*w000 + t0.y*w010 + a100*w100 + b0.y*w110;
                float a001 = sh1 ? t1.y : t1.x;
                float a101 = sh1 ? b1.y : b1.x;
                r1c[c] = a001*w001 + t1.y*w011 + a101*w101 + b1.y*w111;
            }
        }
        #pragma unroll
        for (int c = 0; c < 3; ++c) {
            vf2 rv;
            rv.x = r0c[c];
            rv.y = r1c[c];
            __builtin_nontemporal_store(rv, (vf2*)(ob + (size_t)c*HW + off));
        }
    }
}

extern "C" void kernel_launch(void* const* d_in, const int* in_sizes, int n_in,
                              void* d_out, int out_size, void* d_ws, size_t ws_size,
                              hipStream_t stream) {
    const float* image = (const float*)d_in[0];
    const float* prim  = (const float*)d_in[1];
    float* out = (float*)d_out;

    GaussK gk;
    {
        double sigma = 13.0*0.15 + 0.35;   // 2.3
        double pdf[13], sum = 0.0;
        for (int i = 0; i < 13; ++i) {
            double t = (double)(i - 6);
            pdf[i] = exp(-0.5*(t/sigma)*(t/sigma));
            sum += pdf[i];
        }
        for (int i = 0; i < 13; ++i) gk.k[i] = (float)(pdf[i]/sum);
    }

    k_prep  <<<2048, 256,  0, stream>>>(prim, out, gk);
    k_yssamp<<<NB*8, 1024, 0, stream>>>(image, out, gk);
}

// Round 20
// 226.400 us; speedup vs baseline: 1.4050x; 1.4050x over previous
//
#include <hip/hip_runtime.h>
#include <math.h>

#define HH 512
#define WW 512
#define NB 64
#define HW (HH*WW)

struct GaussK { float k[13]; };

__device__ __forceinline__ float idenv(int i) {
    return (float)(2*i - (WW-1)) / (float)(WW-1);
}

#define DEF_OFF ((float)((2.0 + 4.0/511.0)/2.0))
#define BOUND   ((float)(2.0/512.0*8.0))

typedef float vf2 __attribute__((ext_vector_type(2), aligned(4)));

// horizontal 13-tap conv of one row held as a[8] per lane (cols 8l..8l+7),
// halo via neighbor-lane shuffles, reflect at row ends.
__device__ __forceinline__ void hconv_row(const float (&a)[8], int lane, const GaussK& gk, float (&o)[8]) {
    float win[20];
    #pragma unroll
    for (int i = 0; i < 6; ++i) {
        float v = __shfl_up(a[i+2], 1, 64);
        win[i] = (lane == 0) ? a[6-i] : v;
    }
    #pragma unroll
    for (int i = 6; i < 14; ++i) win[i] = a[i-6];
    #pragma unroll
    for (int i = 14; i < 20; ++i) {
        float v = __shfl_down(a[i-14], 1, 64);
        win[i] = (lane == 63) ? a[20-i] : v;
    }
    #pragma unroll
    for (int j = 0; j < 8; ++j) {
        float acc = 0.f;
        #pragma unroll
        for (int i = 0; i < 13; ++i) acc = fmaf(gk.k[i], win[j+i], acc);
        o[j] = acc;
    }
}

// x-channel pipeline for one row: hconv (incl col-1) + relu-diff scan + clips.
__device__ __forceinline__ void xscan_row(const float (&a)[8], int lane, const GaussK& gk, float* row0) {
    float win[21];
    #pragma unroll
    for (int i = 0; i < 7; ++i) {
        float v = __shfl_up(a[i+1], 1, 64);
        win[i] = (lane == 0) ? a[7-i] : v;
    }
    #pragma unroll
    for (int i = 0; i < 8; ++i) win[7+i] = a[i];
    #pragma unroll
    for (int i = 15; i < 21; ++i) {
        float v = __shfl_down(a[i-15], 1, 64);
        win[i] = (lane == 63) ? a[21-i] : v;
    }
    float s[9];
    #pragma unroll
    for (int j = 0; j < 9; ++j) {
        float acc = 0.f;
        #pragma unroll
        for (int i = 0; i < 13; ++i) acc = fmaf(gk.k[i], win[j+i], acc);
        s[j] = acc + idenv(8*lane - 1 + j) + DEF_OFF;
    }
    if (lane == 0) s[0] = 0.f;

    float qs[8], q = 0.f;
    #pragma unroll
    for (int j = 1; j < 9; ++j) { q += fmaxf(s[j] - s[j-1], 0.f); qs[j-1] = q; }
    float inc = q;
    #pragma unroll
    for (int d = 1; d < 64; d <<= 1) {
        float t = __shfl_up(inc, d, 64);
        if (lane >= d) inc += t;
    }
    float excl = inc - q;

    float4 g0, g1;
    float* gp0 = (float*)&g0;
    float* gp1 = (float*)&g1;
    #pragma unroll
    for (int j = 0; j < 8; ++j) {
        int wcol = lane*8 + j;
        float sx = excl + qs[j];
        float p = sx - DEF_OFF - idenv(wcol);
        p = fminf(fmaxf(p, -BOUND), BOUND);
        float g = p + idenv(wcol);
        g = fminf(fmaxf(g, -1.f), 1.f);
        if (j < 4) gp0[j] = g; else gp1[j-4] = g;
    }
    *(float4*)(row0 + lane*8)     = g0;
    *(float4*)(row0 + lane*8 + 4) = g1;
}

// ---- fused prep: vblur(ch0)+hblur+row-scan -> plane0  AND  hblur(ch1) -> plane1 ----
__global__ void __launch_bounds__(256) k_prep(const float* __restrict__ prim, float* __restrict__ out, GaussK gk) {
    int lane = threadIdx.x & 63;
    int bid  = (int)blockIdx.x;                  // 2048 blocks
    int work = (bid & 7)*256 + (bid >> 3);       // XCD-chunked, bijective
    int gw   = work*4 + ((int)threadIdx.x >> 6); // 0..8191
    int b    = gw >> 7;
    int h0   = (gw & 127)*4;

    const float4* src0 = (const float4*)(prim + (size_t)b*2*HW);
    const float*  src1 = prim + ((size_t)b*2 + 1)*HW;
    float* plane0 = out + (size_t)b*3*HW;
    float* plane1 = out + ((size_t)b*3 + 1)*HW;

    float a[4][8];
    #pragma unroll
    for (int r = 0; r < 4; ++r)
        #pragma unroll
        for (int j = 0; j < 8; ++j) a[r][j] = 0.f;

    #pragma unroll
    for (int i = 0; i < 16; ++i) {
        int rr = h0 - 6 + i;
        rr = rr < 0 ? -rr : (rr > HH-1 ? 2*(HH-1) - rr : rr);
        float4 u0 = src0[(size_t)rr*128 + 2*lane];
        float4 u1 = src0[(size_t)rr*128 + 2*lane + 1];
        float vv[8] = {u0.x,u0.y,u0.z,u0.w,u1.x,u1.y,u1.z,u1.w};
        #pragma unroll
        for (int r = 0; r < 4; ++r) {
            if (i >= r && i <= r + 12) {
                #pragma unroll
                for (int j = 0; j < 8; ++j) a[r][j] = fmaf(gk.k[i-r], vv[j], a[r][j]);
            }
        }
    }

    #pragma unroll
    for (int r = 0; r < 4; ++r) {
        const float4* c4 = (const float4*)(src1 + (size_t)(h0+r)*WW);
        float4 u0 = c4[2*lane];
        float4 u1 = c4[2*lane + 1];
        float c[8] = {u0.x,u0.y,u0.z,u0.w,u1.x,u1.y,u1.z,u1.w};
        float o[8];
        hconv_row(c, lane, gk, o);
        float* row1 = plane1 + (size_t)(h0+r)*WW;
        *(float4*)(row1 + lane*8)     = make_float4(o[0],o[1],o[2],o[3]);
        *(float4*)(row1 + lane*8 + 4) = make_float4(o[4],o[5],o[6],o[7]);
    }

    #pragma unroll
    for (int r = 0; r < 4; ++r)
        xscan_row(a[r], lane, gk, plane0 + (size_t)(h0+r)*WW);
}

// ---- fused y-scan + bilinear sample (R16 configuration: session optimum) ----
// 16 waves scan columns (grid-y stays in registers); post-barrier batched
// grid-x loads + gather epilogue; XCD-chunked so each XCD owns 8 batches.
__global__ void __launch_bounds__(1024, 1) k_yssamp(const float* __restrict__ image, float* __restrict__ out, GaussK gk) {
    __shared__ float segsum[16][64];
    int bid  = (int)blockIdx.x;          // 512 blocks
    int work = (bid & 7)*64 + (bid >> 3);// XCD j owns batches j*8..j*8+7
    int b    = work >> 3;
    int wt   = work & 7;
    int lane = threadIdx.x & 63;
    int ws   = threadIdx.x >> 6;         // 0..15
    int w    = wt*64 + lane;
    const float* p1 = out + ((size_t)b*3 + 1)*HW + w;
    int r0 = ws*32;

    float v[45];                          // plane1 rows r0-7 .. r0+37, reflected
    #pragma unroll
    for (int j = 0; j < 45; ++j) {
        int r = r0 - 7 + j;
        r = r < 0 ? -r : (r > HH-1 ? 2*(HH-1) - r : r);
        v[j] = p1[(size_t)r*WW];
    }

    float sprev;
    if (ws == 0) {
        sprev = 0.f;
    } else {
        float acc = 0.f;
        #pragma unroll
        for (int i = 0; i < 13; ++i) acc = fmaf(gk.k[i], v[i], acc);
        sprev = acc + idenv(r0 - 1) + DEF_OFF;
    }

    float q[32];
    float run = 0.f;
    #pragma unroll
    for (int n = 0; n < 32; ++n) {
        float acc = 0.f;
        #pragma unroll
        for (int i = 0; i < 13; ++i) acc = fmaf(gk.k[i], v[n+1+i], acc);
        float s = acc + idenv(r0 + n) + DEF_OFF;
        run += fmaxf(s - sprev, 0.f);
        q[n] = run;
        sprev = s;
    }
    segsum[ws][lane] = run;
    __syncthreads();
    float off = 0.f;
    for (int k = 0; k < ws; ++k) off += segsum[k][lane];

    const float* ib = image + (size_t)b*3*HW;
    float*       ob = out   + (size_t)b*3*HW;

    // batch-load all 32 grid-x values (coalesced; v[] is dead -> VGPRs available)
    float gxv[32];
    #pragma unroll
    for (int n = 0; n < 32; ++n)
        gxv[n] = ob[(size_t)(r0 + n)*WW + w];

    #pragma unroll
    for (int n = 0; n < 32; ++n) {
        int h = r0 + n;
        size_t poff = (size_t)h*WW + w;
        float p = off + q[n] - DEF_OFF - idenv(h);
        p = fminf(fmaxf(p, -BOUND), BOUND);
        float gy = p + idenv(h);
        gy = fminf(fmaxf(gy, -1.f), 1.f);
        float gx = gxv[n];

        float fx = (gx + 1.f) * 0.5f * (float)(WW-1);
        float fy = (gy + 1.f) * 0.5f * (float)(HH-1);
        float x0f = floorf(fx), y0f = floorf(fy);
        float wx = fx - x0f, wy = fy - y0f;
        int x0 = (int)x0f, y0 = (int)y0f;
        int y1 = y0 + 1; if (y1 > HH-1) y1 = HH-1;
        bool shx = x0 > WW-2;               // x0==511 => wx==0 exactly
        int xb = shx ? WW-2 : x0;
        size_t g0 = (size_t)y0*WW + xb;
        size_t g1 = (size_t)y1*WW + xb;
        float w11 = wx*wy;
        float w01 = wx - w11;
        float w10 = wy - w11;
        float w00 = 1.f - wx - wy + w11;
        #pragma unroll
        for (int c = 0; c < 3; ++c) {
            const float* ip = ib + (size_t)c*HW;
            vf2 t  = *(const vf2*)(ip + g0);
            vf2 bo = *(const vf2*)(ip + g1);
            float a00 = shx ? t.y  : t.x;
            float a10 = shx ? bo.y : bo.x;
            float r = a00*w00 + t.y*w01 + a10*w10 + bo.y*w11;
            __builtin_nontemporal_store(r, ob + (size_t)c*HW + poff);
        }
    }
}

extern "C" void kernel_launch(void* const* d_in, const int* in_sizes, int n_in,
                              void* d_out, int out_size, void* d_ws, size_t ws_size,
                              hipStream_t stream) {
    const float* image = (const float*)d_in[0];
    const float* prim  = (const float*)d_in[1];
    float* out = (float*)d_out;

    GaussK gk;
    {
        double sigma = 13.0*0.15 + 0.35;   // 2.3
        double pdf[13], sum = 0.0;
        for (int i = 0; i < 13; ++i) {
            double t = (double)(i - 6);
            pdf[i] = exp(-0.5*(t/sigma)*(t/sigma));
            sum += pdf[i];
        }
        for (int i = 0; i < 13; ++i) gk.k[i] = (float)(pdf[i]/sum);
    }

    k_prep  <<<2048, 256,  0, stream>>>(prim, out, gk);
    k_yssamp<<<NB*8, 1024, 0, stream>>>(image, out, gk);
}

// Round 21
// 223.377 us; speedup vs baseline: 1.4240x; 1.0135x over previous
//
#include <hip/hip_runtime.h>
#include <math.h>

#define HH 512
#define WW 512
#define NB 64
#define HW (HH*WW)

struct GaussK { float k[13]; };

__device__ __forceinline__ float idenv(int i) {
    return (float)(2*i - (WW-1)) / (float)(WW-1);
}

#define DEF_OFF ((float)((2.0 + 4.0/511.0)/2.0))
#define BOUND   ((float)(2.0/512.0*8.0))

typedef float vf2 __attribute__((ext_vector_type(2), aligned(4)));

// horizontal 13-tap conv of one row held as a[8] per lane (cols 8l..8l+7),
// halo via neighbor-lane shuffles, reflect at row ends.
__device__ __forceinline__ void hconv_row(const float (&a)[8], int lane, const GaussK& gk, float (&o)[8]) {
    float win[20];
    #pragma unroll
    for (int i = 0; i < 6; ++i) {
        float v = __shfl_up(a[i+2], 1, 64);
        win[i] = (lane == 0) ? a[6-i] : v;
    }
    #pragma unroll
    for (int i = 6; i < 14; ++i) win[i] = a[i-6];
    #pragma unroll
    for (int i = 14; i < 20; ++i) {
        float v = __shfl_down(a[i-14], 1, 64);
        win[i] = (lane == 63) ? a[20-i] : v;
    }
    #pragma unroll
    for (int j = 0; j < 8; ++j) {
        float acc = 0.f;
        #pragma unroll
        for (int i = 0; i < 13; ++i) acc = fmaf(gk.k[i], win[j+i], acc);
        o[j] = acc;
    }
}

// x-channel pipeline for one row: hconv (incl col-1) + relu-diff scan + clips.
__device__ __forceinline__ void xscan_row(const float (&a)[8], int lane, const GaussK& gk, float* row0) {
    float win[21];
    #pragma unroll
    for (int i = 0; i < 7; ++i) {
        float v = __shfl_up(a[i+1], 1, 64);
        win[i] = (lane == 0) ? a[7-i] : v;
    }
    #pragma unroll
    for (int i = 0; i < 8; ++i) win[7+i] = a[i];
    #pragma unroll
    for (int i = 15; i < 21; ++i) {
        float v = __shfl_down(a[i-15], 1, 64);
        win[i] = (lane == 63) ? a[21-i] : v;
    }
    float s[9];
    #pragma unroll
    for (int j = 0; j < 9; ++j) {
        float acc = 0.f;
        #pragma unroll
        for (int i = 0; i < 13; ++i) acc = fmaf(gk.k[i], win[j+i], acc);
        s[j] = acc + idenv(8*lane - 1 + j) + DEF_OFF;
    }
    if (lane == 0) s[0] = 0.f;

    float qs[8], q = 0.f;
    #pragma unroll
    for (int j = 1; j < 9; ++j) { q += fmaxf(s[j] - s[j-1], 0.f); qs[j-1] = q; }
    float inc = q;
    #pragma unroll
    for (int d = 1; d < 64; d <<= 1) {
        float t = __shfl_up(inc, d, 64);
        if (lane >= d) inc += t;
    }
    float excl = inc - q;

    float4 g0, g1;
    float* gp0 = (float*)&g0;
    float* gp1 = (float*)&g1;
    #pragma unroll
    for (int j = 0; j < 8; ++j) {
        int wcol = lane*8 + j;
        float sx = excl + qs[j];
        float p = sx - DEF_OFF - idenv(wcol);
        p = fminf(fmaxf(p, -BOUND), BOUND);
        float g = p + idenv(wcol);
        g = fminf(fmaxf(g, -1.f), 1.f);
        if (j < 4) gp0[j] = g; else gp1[j-4] = g;
    }
    *(float4*)(row0 + lane*8)     = g0;
    *(float4*)(row0 + lane*8 + 4) = g1;
}

// ---- fused prep: vblur(ch0)+hblur+row-scan -> plane0  AND  hblur(ch1) -> plane1 ----
__global__ void __launch_bounds__(256) k_prep(const float* __restrict__ prim, float* __restrict__ out, GaussK gk) {
    int lane = threadIdx.x & 63;
    int bid  = (int)blockIdx.x;                  // 2048 blocks
    int work = (bid & 7)*256 + (bid >> 3);       // XCD-chunked, bijective
    int gw   = work*4 + ((int)threadIdx.x >> 6); // 0..8191
    int b    = gw >> 7;
    int h0   = (gw & 127)*4;

    const float4* src0 = (const float4*)(prim + (size_t)b*2*HW);
    const float*  src1 = prim + ((size_t)b*2 + 1)*HW;
    float* plane0 = out + (size_t)b*3*HW;
    float* plane1 = out + ((size_t)b*3 + 1)*HW;

    float a[4][8];
    #pragma unroll
    for (int r = 0; r < 4; ++r)
        #pragma unroll
        for (int j = 0; j < 8; ++j) a[r][j] = 0.f;

    #pragma unroll
    for (int i = 0; i < 16; ++i) {
        int rr = h0 - 6 + i;
        rr = rr < 0 ? -rr : (rr > HH-1 ? 2*(HH-1) - rr : rr);
        float4 u0 = src0[(size_t)rr*128 + 2*lane];
        float4 u1 = src0[(size_t)rr*128 + 2*lane + 1];
        float vv[8] = {u0.x,u0.y,u0.z,u0.w,u1.x,u1.y,u1.z,u1.w};
        #pragma unroll
        for (int r = 0; r < 4; ++r) {
            if (i >= r && i <= r + 12) {
                #pragma unroll
                for (int j = 0; j < 8; ++j) a[r][j] = fmaf(gk.k[i-r], vv[j], a[r][j]);
            }
        }
    }

    #pragma unroll
    for (int r = 0; r < 4; ++r) {
        const float4* c4 = (const float4*)(src1 + (size_t)(h0+r)*WW);
        float4 u0 = c4[2*lane];
        float4 u1 = c4[2*lane + 1];
        float c[8] = {u0.x,u0.y,u0.z,u0.w,u1.x,u1.y,u1.z,u1.w};
        float o[8];
        hconv_row(c, lane, gk, o);
        float* row1 = plane1 + (size_t)(h0+r)*WW;
        *(float4*)(row1 + lane*8)     = make_float4(o[0],o[1],o[2],o[3]);
        *(float4*)(row1 + lane*8 + 4) = make_float4(o[4],o[5],o[6],o[7]);
    }

    #pragma unroll
    for (int r = 0; r < 4; ++r)
        xscan_row(a[r], lane, gk, plane0 + (size_t)(h0+r)*WW);
}

// ---- fused y-scan + bilinear sample, gather epilogue batched 4 rows deep ----
// Identical to the session-optimum kernel except the epilogue issues all 24
// gathers of a 4-row group into named registers before the first blend
// (forces ~24 loads in flight per wave instead of the allocator's ~6).
__global__ void __launch_bounds__(1024, 1) k_yssamp(const float* __restrict__ image, float* __restrict__ out, GaussK gk) {
    __shared__ float segsum[16][64];
    int bid  = (int)blockIdx.x;          // 512 blocks
    int work = (bid & 7)*64 + (bid >> 3);// XCD j owns batches j*8..j*8+7
    int b    = work >> 3;
    int wt   = work & 7;
    int lane = threadIdx.x & 63;
    int ws   = threadIdx.x >> 6;         // 0..15
    int w    = wt*64 + lane;
    const float* p1 = out + ((size_t)b*3 + 1)*HW + w;
    int r0 = ws*32;

    float v[45];                          // plane1 rows r0-7 .. r0+37, reflected
    #pragma unroll
    for (int j = 0; j < 45; ++j) {
        int r = r0 - 7 + j;
        r = r < 0 ? -r : (r > HH-1 ? 2*(HH-1) - r : r);
        v[j] = p1[(size_t)r*WW];
    }

    float sprev;
    if (ws == 0) {
        sprev = 0.f;
    } else {
        float acc = 0.f;
        #pragma unroll
        for (int i = 0; i < 13; ++i) acc = fmaf(gk.k[i], v[i], acc);
        sprev = acc + idenv(r0 - 1) + DEF_OFF;
    }

    float q[32];
    float run = 0.f;
    #pragma unroll
    for (int n = 0; n < 32; ++n) {
        float acc = 0.f;
        #pragma unroll
        for (int i = 0; i < 13; ++i) acc = fmaf(gk.k[i], v[n+1+i], acc);
        float s = acc + idenv(r0 + n) + DEF_OFF;
        run += fmaxf(s - sprev, 0.f);
        q[n] = run;
        sprev = s;
    }
    segsum[ws][lane] = run;
    __syncthreads();
    float off = 0.f;
    for (int k = 0; k < ws; ++k) off += segsum[k][lane];

    const float* ib = image + (size_t)b*3*HW;
    float*       ob = out   + (size_t)b*3*HW;

    // batch-load all 32 grid-x values (coalesced; v[] is dead -> VGPRs available)
    float gxv[32];
    #pragma unroll
    for (int n = 0; n < 32; ++n)
        gxv[n] = ob[(size_t)(r0 + n)*WW + w];

    #pragma unroll
    for (int g = 0; g < 8; ++g) {
        float W00[4], W01[4], W10[4], W11[4];
        bool  SH[4];
        vf2   T[4][3], B[4][3];
        #pragma unroll
        for (int r = 0; r < 4; ++r) {
            int n = g*4 + r;
            int h = r0 + n;
            float p = off + q[n] - DEF_OFF - idenv(h);
            p = fminf(fmaxf(p, -BOUND), BOUND);
            float gy = fminf(fmaxf(p + idenv(h), -1.f), 1.f);
            float gx = gxv[n];

            float fx = (gx + 1.f) * 0.5f * (float)(WW-1);
            float fy = (gy + 1.f) * 0.5f * (float)(HH-1);
            float x0f = floorf(fx), y0f = floorf(fy);
            float wx = fx - x0f, wy = fy - y0f;
            int x0 = (int)x0f, y0 = (int)y0f;
            int y1 = y0 + 1; if (y1 > HH-1) y1 = HH-1;
            bool shx = x0 > WW-2;            // x0==511 => wx==0 exactly
            int xb = shx ? WW-2 : x0;
            size_t gt = (size_t)y0*WW + xb;
            size_t gb = (size_t)y1*WW + xb;
            SH[r] = shx;
            float w11 = wx*wy;
            W11[r] = w11;
            W01[r] = wx - w11;
            W10[r] = wy - w11;
            W00[r] = 1.f - wx - wy + w11;
            #pragma unroll
            for (int c = 0; c < 3; ++c) {
                const float* ip = ib + (size_t)c*HW;
                T[r][c] = *(const vf2*)(ip + gt);
                B[r][c] = *(const vf2*)(ip + gb);
            }
        }
        #pragma unroll
        for (int r = 0; r < 4; ++r) {
            int n = g*4 + r;
            int h = r0 + n;
            size_t poff = (size_t)h*WW + w;
            #pragma unroll
            for (int c = 0; c < 3; ++c) {
                float a00 = SH[r] ? T[r][c].y : T[r][c].x;
                float a10 = SH[r] ? B[r][c].y : B[r][c].x;
                float res = a00*W00[r] + T[r][c].y*W01[r] + a10*W10[r] + B[r][c].y*W11[r];
                __builtin_nontemporal_store(res, ob + (size_t)c*HW + poff);
            }
        }
    }
}

extern "C" void kernel_launch(void* const* d_in, const int* in_sizes, int n_in,
                              void* d_out, int out_size, void* d_ws, size_t ws_size,
                              hipStream_t stream) {
    const float* image = (const float*)d_in[0];
    const float* prim  = (const float*)d_in[1];
    float* out = (float*)d_out;

    GaussK gk;
    {
        double sigma = 13.0*0.15 + 0.35;   // 2.3
        double pdf[13], sum = 0.0;
        for (int i = 0; i < 13; ++i) {
            double t = (double)(i - 6);
            pdf[i] = exp(-0.5*(t/sigma)*(t/sigma));
            sum += pdf[i];
        }
        for (int i = 0; i < 13; ++i) gk.k[i] = (float)(pdf[i]/sum);
    }

    k_prep  <<<2048, 256,  0, stream>>>(prim, out, gk);
    k_yssamp<<<NB*8, 1024, 0, stream>>>(image, out, gk);
}